// Round 11
// baseline (185.944 us; speedup 1.0000x reference)
//
#include <hip/hip_runtime.h>
#include <math.h>

#define HH 1080
#define WW 1920
#define RAD 5
#define TX 32
#define TY 20            // 1080/20 = 54 exact; LDS 35280B -> 4 blocks x 5 waves = 20 waves/CU
#define RPT 2            // 2 boundary rows instead of 4: 132 executed bodies/output vs 143
#define BDY 10           // 32x10 = 320 threads = 5 waves
#define LR (TY + 2*RAD)  // 30
#define LC (TX + 2*RAD)  // 42

__device__ __forceinline__ float fast_rcp(float x) {
#if __has_builtin(__builtin_amdgcn_rcpf)
    return __builtin_amdgcn_rcpf(x);
#else
    return 1.0f / x;
#endif
}
__device__ __forceinline__ float fast_rsq(float x) {
#if __has_builtin(__builtin_amdgcn_rsqf)
    return __builtin_amdgcn_rsqf(x);
#else
    return rsqrtf(x);
#endif
}
__device__ __forceinline__ float fast_exp2(float x) {
#if __has_builtin(__builtin_amdgcn_exp2f)
    return __builtin_amdgcn_exp2f(x);
#else
    return exp2f(x);
#endif
}

// Weight: w = exp(-d2/8) * clip(dot,0,1)^128 * exp(-|tz-z| / max(dz*sqrt(d2), 1e-4))
// One exp2; quadratic ln(1+t) ~= t - t^2/2 for the ^128 term with t = dot-1 folded out:
//   e2 = fma(dot, fma(dot, -C/2, 2C), e2a'),  C = 128*log2e
//   e2a' = fma(-|zd|, tm[d2], cx'[d2]),  cx'[d2] = -d2*log2e/8 - 1.5C
//   tm[d2] = min(rdz*rsqrt(d2), 1e4*log2e),  rdz = min(log2e*rcp(dz), 1e10)
// tm tables RATIO-CHAIN across tap-rows (one step at RPT=2): tm[o=1] at row r equals
// tm[o=0] at row r-1 scaled by rr1 = rdz[1]/rdz[0] (cancels exactly); only tmu0 fresh
// (6 rsq/row). Clamp AFTER chaining. rdz clamp keeps rr1 finite-positive.
// Center tap: rsqrt(0)=inf -> tm=BIG; zd==0 -> fma(-0,BIG,cx)=cx; dot==1 -> w=1. Exact.
// dot=0 (clip / zero-padded halo mask) -> e2 <= -277 -> w=0 == reference t_m mask.
// Validated fusion numerics R2-R10: absmax 3.9e-3 vs threshold 2e-2.
// Lessons: R2 never fully unroll the row loop; R4 registers not LDS for tables;
// R9/R10 deep loop-carried chains attract scratch - keep chain state minimal.

__global__ __launch_bounds__(TX*BDY, 5)
void denoise_kernel(const float* __restrict__ in, float* __restrict__ out) {
    __shared__ float4 sA[LR][LC];   // c0,c1,c2,n0   20160 B
    __shared__ float2 sN[LR][LC];   // n1,n2         10080 B
    __shared__ float  sZ[LR][LC];   // z              5040 B -> 35280 B -> 4 blocks/CU

    const int tx = threadIdx.x;
    const int ty = threadIdx.y;
    const int tid = ty * TX + tx;
    const int x0 = blockIdx.x * TX;
    const int y0 = blockIdx.y * TY;

    // ---- stage tile + halo, normalizing normals on the fly ----
    #pragma unroll
    for (int i = 0; i < (LR * LC + TX * BDY - 1) / (TX * BDY); ++i) {
        int idx = tid + i * (TX * BDY);
        if (idx < LR * LC) {
            int r = idx / LC, c = idx % LC;
            int gx = x0 + c - RAD;
            int gy = y0 + r - RAD;
            float4 a = make_float4(0.f, 0.f, 0.f, 0.f);
            float4 b = make_float4(0.f, 0.f, 0.f, 0.f);
            if ((unsigned)gx < (unsigned)WW && (unsigned)gy < (unsigned)HH) {
                const float4* p = reinterpret_cast<const float4*>(in + ((size_t)gy * WW + gx) * 8);
                a = p[0];
                b = p[1];
            }
            float nn = a.w * a.w + b.x * b.x + b.y * b.y;
            float s = fast_rsq(fmaxf(nn, 1e-20f));
            sA[r][c] = make_float4(a.x, a.y, a.z, a.w * s);
            sN[r][c] = make_float2(b.x * s, b.y * s);
            sZ[r][c] = b.z;
        }
    }
    __syncthreads();

    // ---- per-thread centers: 2 vertically adjacent outputs ----
    float cn0[RPT], cn1[RPT], cn2[RPT], cz[RPT], rdz[RPT];
    #pragma unroll
    for (int o = 0; o < RPT; ++o) {
        int rr = ty * RPT + RAD + o, cc = tx + RAD;
        float4 A = sA[rr][cc];
        float2 N = sN[rr][cc];
        cn0[o] = A.w; cn1[o] = N.x; cn2[o] = N.y; cz[o] = sZ[rr][cc];
        int gy = y0 + ty * RPT + o;       // always < HH (1080 = 54*20 exact)
        float dzv = in[(((size_t)gy * WW) + (x0 + tx)) * 8 + 7];
        rdz[o] = fminf(1.4426950408889634f * fast_rcp(dzv), 1e10f);  // log2e folded; finite
    }
    const float rr1 = rdz[1] * fast_rcp(rdz[0]);   // chain ratio, finite positive

    float accx[RPT] = {0.f, 0.f};
    float accy[RPT] = {0.f, 0.f};
    float accz[RPT] = {0.f, 0.f};
    float accw[RPT] = {0.f, 0.f};

    // unclamped tm chain state (zero-init: invalid slots chain to 0, gated by val[])
    float tmu0[RAD + 1] = {}, tmu1[RAD + 1] = {};

    // ROW_BODY(CHECK): one tap-row. Rotate the 1-step tm chain, compute 6 fresh rsq
    // for o=0's new dy, clamp into tmv (value-select, compile-time (o,k)), build cxv,
    // then 11 x RPT unrolled bodies with compile-time k = |dx-RAD|.
    // Steady body: 11 VALU + 1 exp2.
    #define ROW_BODY(CHECK)                                                          \
    {                                                                                \
        _Pragma("unroll")                                                            \
        for (int k = 0; k <= RAD; ++k) tmu1[k] = tmu0[k] * rr1;                      \
        if (!CHECK || r <= 2 * RAD) {   /* fresh dy only while it can become valid */\
            int dy0 = r - RAD;                                                      \
            float dy0sq = (float)(dy0 * dy0);                                       \
            _Pragma("unroll")                                                       \
            for (int k = 0; k <= RAD; ++k)                                          \
                tmu0[k] = rdz[0] * fast_rsq(dy0sq + (float)(k * k));                \
        }                                                                            \
        float tmv[RPT][RAD + 1], cxv[RPT][RAD + 1];                                  \
        bool  val[RPT];                                                              \
        _Pragma("unroll")                                                            \
        for (int o = 0; o < RPT; ++o) {                                              \
            int dy = r - RAD - o;                                                    \
            val[o] = (dy >= -RAD) && (dy <= RAD);                                    \
            if (!CHECK || val[o]) {                                                  \
                float dy2f = (float)(dy * dy);                                       \
                float bneg = fmaf(dy2f, -0.18033688011112042f, -276.997447850681f);  \
                _Pragma("unroll")                                                    \
                for (int k = 0; k <= RAD; ++k) {                                     \
                    float tmuk = (o == 0) ? tmu0[k] : tmu1[k];                       \
                    cxv[o][k] = bneg + (float)(k * k) * -0.18033688011112042f;       \
                    tmv[o][k] = fminf(tmuk, 14426.950408889634f);                    \
                }                                                                    \
            }                                                                        \
        }                                                                            \
        _Pragma("unroll")                                                            \
        for (int dx = 0; dx < 2 * RAD + 1; ++dx) {                                   \
            float4 A  = sA[ty * RPT + r][tx + dx];                                   \
            float2 N  = sN[ty * RPT + r][tx + dx];                                   \
            float  tz = sZ[ty * RPT + r][tx + dx];                                   \
            const int k = (dx < RAD) ? (RAD - dx) : (dx - RAD);                      \
            _Pragma("unroll")                                                        \
            for (int o = 0; o < RPT; ++o) {                                          \
                if (!CHECK || val[o]) {                                              \
                    float dot = fmaf(A.w, cn0[o], fmaf(N.x, cn1[o], N.y * cn2[o]));  \
                    float vv  = fmaf(dot, -92.332482616893665f, 369.32993046757466f); \
                    float zd  = tz - cz[o];                                          \
                    float e2a = fmaf(-fabsf(zd), tmv[o][k], cxv[o][k]);              \
                    float e2  = fmaf(dot, vv, e2a);                                  \
                    float w   = fast_exp2(e2);                                       \
                    accx[o] = fmaf(A.x, w, accx[o]);                                 \
                    accy[o] = fmaf(A.y, w, accy[o]);                                 \
                    accz[o] = fmaf(A.z, w, accz[o]);                                 \
                    accw[o] += w;                                                    \
                }                                                                    \
            }                                                                        \
        }                                                                            \
    }

    // ---- boundary head: r=0 (o=1 invalid) ----
    #pragma unroll 1
    for (int r = 0; r < RPT - 1; ++r) ROW_BODY(true)
    // ---- steady rows r in [1,10]: both outputs valid, branch-free ----
    #pragma unroll 1
    for (int r = RPT - 1; r <= 2 * RAD; ++r) ROW_BODY(false)
    // ---- boundary tail: r=11 (o=0 invalid) ----
    #pragma unroll 1
    for (int r = 2 * RAD + 1; r < 2 * RAD + RPT; ++r) ROW_BODY(true)

    #undef ROW_BODY

    // ---- epilogue ----
    const int xo = x0 + tx;
    #pragma unroll
    for (int o = 0; o < RPT; ++o) {
        int y = y0 + ty * RPT + o;       // always < HH
        float inv = fast_rcp(accw[o]);
        size_t base = ((size_t)y * WW + xo) * 3;
        out[base + 0] = accx[o] * inv;
        out[base + 1] = accy[o] * inv;
        out[base + 2] = accz[o] * inv;
    }
}

extern "C" void kernel_launch(void* const* d_in, const int* in_sizes, int n_in,
                              void* d_out, int out_size, void* d_ws, size_t ws_size,
                              hipStream_t stream) {
    const float* in = (const float*)d_in[0];
    float* out = (float*)d_out;
    dim3 grid((WW + TX - 1) / TX, HH / TY);               // 60 x 54
    dim3 block(TX, BDY);                                  // 320 threads = 5 waves
    hipLaunchKernelGGL(denoise_kernel, grid, block, 0, stream, in, out);
}

// Round 12
// 126.840 us; speedup vs baseline: 1.4660x; 1.4660x over previous
//
#include <hip/hip_runtime.h>
#include <math.h>

#define HH 1080
#define WW 1920
#define RAD 5
#define TX 32
#define TY 20            // 1080/20 = 54 exact; LDS 35280B -> 4 blocks x 5 waves = 20 waves/CU
#define RPT 2
#define BDY 10           // 32x10 = 320 threads = 5 waves
#define LR (TY + 2*RAD)  // 30
#define LC (TX + 2*RAD)  // 42

__device__ __forceinline__ float fast_rcp(float x) {
#if __has_builtin(__builtin_amdgcn_rcpf)
    return __builtin_amdgcn_rcpf(x);
#else
    return 1.0f / x;
#endif
}
__device__ __forceinline__ float fast_rsq(float x) {
#if __has_builtin(__builtin_amdgcn_rsqf)
    return __builtin_amdgcn_rsqf(x);
#else
    return rsqrtf(x);
#endif
}
__device__ __forceinline__ float fast_exp2(float x) {
#if __has_builtin(__builtin_amdgcn_exp2f)
    return __builtin_amdgcn_exp2f(x);
#else
    return exp2f(x);
#endif
}

// Weight: w = exp(-d2/8) * clip(dot,0,1)^128 * exp(-|tz-z| / max(dz*sqrt(d2), 1e-4))
// One exp2; quadratic ln(1+t) ~= t - t^2/2 for the ^128 term with t = dot-1 folded out:
//   e2 = fma(dot, fma(dot, -C/2, 2C), e2a'),  C = 128*log2e
//   e2a' = fma(-|zd|, tm[d2], cx'[d2]),  cx'[d2] = -d2*log2e/8 - 1.5C
//   tm[d2] = min(rdz*rsqrt(d2), 1e4*log2e),  rdz = min(log2e*rcp(dz), 1e10)
// tm tables RATIO-CHAIN across tap-rows (one step at RPT=2): tm[o=1] at row r equals
// tm[o=0] at row r-1 scaled by rr1 = rdz[1]/rdz[0] (cancels exactly); only tmu0 fresh
// (6 rsq/row). Clamp AFTER chaining. rdz clamp keeps rr1 finite-positive.
// Center tap: rsqrt(0)=inf -> tm=BIG; zd==0 -> fma(-0,BIG,cx)=cx; dot==1 -> w=1. Exact.
// dot=0 (clip / zero-padded halo mask) -> e2 <= -277 -> w=0 == reference t_m mask.
// Validated fusion numerics R2-R11: absmax 3.9e-3 vs threshold 2e-2.
// Lessons: R2 never fully unroll the row loop; R4 registers not LDS for tables;
// R9/R10 keep loop-carried chain state minimal (scratch risk);
// R11 NEVER demand waves via launch_bounds' 2nd arg beyond natural VGPR fit --
//     (320,5) forced VGPR=48 and 233MB of spill traffic. Use 4 and let LDS cap.

__global__ __launch_bounds__(TX*BDY, 4)
void denoise_kernel(const float* __restrict__ in, float* __restrict__ out) {
    __shared__ float4 sA[LR][LC];   // c0,c1,c2,n0   20160 B
    __shared__ float2 sN[LR][LC];   // n1,n2         10080 B
    __shared__ float  sZ[LR][LC];   // z              5040 B -> 35280 B -> 4 blocks/CU

    const int tx = threadIdx.x;
    const int ty = threadIdx.y;
    const int tid = ty * TX + tx;
    const int x0 = blockIdx.x * TX;
    const int y0 = blockIdx.y * TY;

    // ---- stage tile + halo, normalizing normals on the fly ----
    #pragma unroll
    for (int i = 0; i < (LR * LC + TX * BDY - 1) / (TX * BDY); ++i) {
        int idx = tid + i * (TX * BDY);
        if (idx < LR * LC) {
            int r = idx / LC, c = idx % LC;
            int gx = x0 + c - RAD;
            int gy = y0 + r - RAD;
            float4 a = make_float4(0.f, 0.f, 0.f, 0.f);
            float4 b = make_float4(0.f, 0.f, 0.f, 0.f);
            if ((unsigned)gx < (unsigned)WW && (unsigned)gy < (unsigned)HH) {
                const float4* p = reinterpret_cast<const float4*>(in + ((size_t)gy * WW + gx) * 8);
                a = p[0];
                b = p[1];
            }
            float nn = a.w * a.w + b.x * b.x + b.y * b.y;
            float s = fast_rsq(fmaxf(nn, 1e-20f));
            sA[r][c] = make_float4(a.x, a.y, a.z, a.w * s);
            sN[r][c] = make_float2(b.x * s, b.y * s);
            sZ[r][c] = b.z;
        }
    }
    __syncthreads();

    // ---- per-thread centers: 2 vertically adjacent outputs ----
    float cn0[RPT], cn1[RPT], cn2[RPT], cz[RPT], rdz[RPT];
    #pragma unroll
    for (int o = 0; o < RPT; ++o) {
        int rr = ty * RPT + RAD + o, cc = tx + RAD;
        float4 A = sA[rr][cc];
        float2 N = sN[rr][cc];
        cn0[o] = A.w; cn1[o] = N.x; cn2[o] = N.y; cz[o] = sZ[rr][cc];
        int gy = y0 + ty * RPT + o;       // always < HH (1080 = 54*20 exact)
        float dzv = in[(((size_t)gy * WW) + (x0 + tx)) * 8 + 7];
        rdz[o] = fminf(1.4426950408889634f * fast_rcp(dzv), 1e10f);  // log2e folded; finite
    }
    const float rr1 = rdz[1] * fast_rcp(rdz[0]);   // chain ratio, finite positive

    float accx[RPT] = {0.f, 0.f};
    float accy[RPT] = {0.f, 0.f};
    float accz[RPT] = {0.f, 0.f};
    float accw[RPT] = {0.f, 0.f};

    // unclamped tm chain state (zero-init: invalid slots chain to 0, gated by val[])
    float tmu0[RAD + 1] = {}, tmu1[RAD + 1] = {};

    // ROW_BODY(CHECK): one tap-row. Rotate the 1-step tm chain, compute 6 fresh rsq
    // for o=0's new dy, clamp into tmv (value-select, compile-time (o,k)), build cxv,
    // then 11 x RPT unrolled bodies with compile-time k = |dx-RAD|.
    // Steady body: 11 VALU + 1 exp2.
    #define ROW_BODY(CHECK)                                                          \
    {                                                                                \
        _Pragma("unroll")                                                            \
        for (int k = 0; k <= RAD; ++k) tmu1[k] = tmu0[k] * rr1;                      \
        if (!CHECK || r <= 2 * RAD) {   /* fresh dy only while it can become valid */\
            int dy0 = r - RAD;                                                      \
            float dy0sq = (float)(dy0 * dy0);                                       \
            _Pragma("unroll")                                                       \
            for (int k = 0; k <= RAD; ++k)                                          \
                tmu0[k] = rdz[0] * fast_rsq(dy0sq + (float)(k * k));                \
        }                                                                            \
        float tmv[RPT][RAD + 1], cxv[RPT][RAD + 1];                                  \
        bool  val[RPT];                                                              \
        _Pragma("unroll")                                                            \
        for (int o = 0; o < RPT; ++o) {                                              \
            int dy = r - RAD - o;                                                    \
            val[o] = (dy >= -RAD) && (dy <= RAD);                                    \
            if (!CHECK || val[o]) {                                                  \
                float dy2f = (float)(dy * dy);                                       \
                float bneg = fmaf(dy2f, -0.18033688011112042f, -276.997447850681f);  \
                _Pragma("unroll")                                                    \
                for (int k = 0; k <= RAD; ++k) {                                     \
                    float tmuk = (o == 0) ? tmu0[k] : tmu1[k];                       \
                    cxv[o][k] = bneg + (float)(k * k) * -0.18033688011112042f;       \
                    tmv[o][k] = fminf(tmuk, 14426.950408889634f);                    \
                }                                                                    \
            }                                                                        \
        }                                                                            \
        _Pragma("unroll")                                                            \
        for (int dx = 0; dx < 2 * RAD + 1; ++dx) {                                   \
            float4 A  = sA[ty * RPT + r][tx + dx];                                   \
            float2 N  = sN[ty * RPT + r][tx + dx];                                   \
            float  tz = sZ[ty * RPT + r][tx + dx];                                   \
            const int k = (dx < RAD) ? (RAD - dx) : (dx - RAD);                      \
            _Pragma("unroll")                                                        \
            for (int o = 0; o < RPT; ++o) {                                          \
                if (!CHECK || val[o]) {                                              \
                    float dot = fmaf(A.w, cn0[o], fmaf(N.x, cn1[o], N.y * cn2[o]));  \
                    float vv  = fmaf(dot, -92.332482616893665f, 369.32993046757466f); \
                    float zd  = tz - cz[o];                                          \
                    float e2a = fmaf(-fabsf(zd), tmv[o][k], cxv[o][k]);              \
                    float e2  = fmaf(dot, vv, e2a);                                  \
                    float w   = fast_exp2(e2);                                       \
                    accx[o] = fmaf(A.x, w, accx[o]);                                 \
                    accy[o] = fmaf(A.y, w, accy[o]);                                 \
                    accz[o] = fmaf(A.z, w, accz[o]);                                 \
                    accw[o] += w;                                                    \
                }                                                                    \
            }                                                                        \
        }                                                                            \
    }

    // ---- boundary head: r=0 (o=1 invalid) ----
    #pragma unroll 1
    for (int r = 0; r < RPT - 1; ++r) ROW_BODY(true)
    // ---- steady rows r in [1,10]: both outputs valid, branch-free ----
    #pragma unroll 1
    for (int r = RPT - 1; r <= 2 * RAD; ++r) ROW_BODY(false)
    // ---- boundary tail: r=11 (o=0 invalid) ----
    #pragma unroll 1
    for (int r = 2 * RAD + 1; r < 2 * RAD + RPT; ++r) ROW_BODY(true)

    #undef ROW_BODY

    // ---- epilogue ----
    const int xo = x0 + tx;
    #pragma unroll
    for (int o = 0; o < RPT; ++o) {
        int y = y0 + ty * RPT + o;       // always < HH
        float inv = fast_rcp(accw[o]);
        size_t base = ((size_t)y * WW + xo) * 3;
        out[base + 0] = accx[o] * inv;
        out[base + 1] = accy[o] * inv;
        out[base + 2] = accz[o] * inv;
    }
}

extern "C" void kernel_launch(void* const* d_in, const int* in_sizes, int n_in,
                              void* d_out, int out_size, void* d_ws, size_t ws_size,
                              hipStream_t stream) {
    const float* in = (const float*)d_in[0];
    float* out = (float*)d_out;
    dim3 grid((WW + TX - 1) / TX, HH / TY);               // 60 x 54
    dim3 block(TX, BDY);                                  // 320 threads = 5 waves
    hipLaunchKernelGGL(denoise_kernel, grid, block, 0, stream, in, out);
}

// Round 13
// 106.376 us; speedup vs baseline: 1.7480x; 1.1924x over previous
//
#include <hip/hip_runtime.h>
#include <math.h>

#define HH 1080
#define WW 1920
#define RAD 5
#define TX 32
#define TY 16            // 16 rows/block; LDS 30720B -> 5 blocks x 4 waves = 20 waves/CU
#define RPT 2
#define BDY 8            // 32x8 = 256 threads = 4 waves (R12 lesson: keep 4-wave blocks)
#define LR (TY + 2*RAD)  // 26
#define LC (TX + 2*RAD)  // 42

__device__ __forceinline__ float fast_rcp(float x) {
#if __has_builtin(__builtin_amdgcn_rcpf)
    return __builtin_amdgcn_rcpf(x);
#else
    return 1.0f / x;
#endif
}
__device__ __forceinline__ float fast_rsq(float x) {
#if __has_builtin(__builtin_amdgcn_rsqf)
    return __builtin_amdgcn_rsqf(x);
#else
    return rsqrtf(x);
#endif
}
__device__ __forceinline__ float fast_exp2(float x) {
#if __has_builtin(__builtin_amdgcn_exp2f)
    return __builtin_amdgcn_exp2f(x);
#else
    return exp2f(x);
#endif
}

// Weight: w = exp(-d2/8) * clip(dot,0,1)^128 * exp(-|tz-z| / max(dz*sqrt(d2), 1e-4))
// One exp2; quadratic ln(1+t) ~= t - t^2/2 for the ^128 term with t = dot-1 folded out:
//   e2 = fma(dot, fma(dot, -C/2, 2C), e2a'),  C = 128*log2e
//   e2a' = fma(-|zd|, tm[d2], cx'[d2]),  cx'[d2] = -d2*log2e/8 - 1.5C
//   tm[d2] = min(rdz*rsqrt(d2), 1e4*log2e),  rdz = min(log2e*rcp(dz), 1e10)
// tm tables RATIO-CHAIN across tap-rows (one step at RPT=2): tm[o=1] at row r equals
// tm[o=0] at row r-1 scaled by rr1 = rdz[1]/rdz[0] (cancels exactly); only tmu0 fresh
// (6 rsq/row). Clamp AFTER chaining. rdz clamp keeps rr1 finite-positive.
// Center tap: rsqrt(0)=inf -> tm=BIG; zd==0 -> fma(-0,BIG,cx)=cx; dot==1 -> w=1. Exact.
// dot=0 (clip / zero-padded halo mask) -> e2 <= -277 -> w=0 == reference t_m mask.
// Validated fusion numerics R2-R12: absmax 3.9e-3 vs threshold 2e-2.
// Lessons: R2 never fully unroll the row loop; R4 registers not LDS for tables;
// R9/R10 keep loop-carried chain state minimal (scratch risk);
// R11 never demand waves via launch_bounds beyond natural VGPR fit (forced spill);
// R12 5-wave (320-thr) workgroups broke co-residency (occ 22%) -- 4-wave blocks only,
//     get occupancy through LDS size (5 blocks x 4 waves here).

__global__ __launch_bounds__(TX*BDY, 4)
void denoise_kernel(const float* __restrict__ in, float* __restrict__ out) {
    __shared__ float4 sA[LR][LC];   // c0,c1,c2,n0   17472 B
    __shared__ float2 sN[LR][LC];   // n1,n2          8736 B
    __shared__ float  sZ[LR][LC];   // z              4368 B -> 30576 B -> 5 blocks/CU

    const int tx = threadIdx.x;
    const int ty = threadIdx.y;
    const int tid = ty * TX + tx;
    const int x0 = blockIdx.x * TX;
    const int y0 = blockIdx.y * TY;

    // ---- stage tile + halo, normalizing normals on the fly ----
    #pragma unroll
    for (int i = 0; i < (LR * LC + TX * BDY - 1) / (TX * BDY); ++i) {
        int idx = tid + i * (TX * BDY);
        if (idx < LR * LC) {
            int r = idx / LC, c = idx % LC;
            int gx = x0 + c - RAD;
            int gy = y0 + r - RAD;
            float4 a = make_float4(0.f, 0.f, 0.f, 0.f);
            float4 b = make_float4(0.f, 0.f, 0.f, 0.f);
            if ((unsigned)gx < (unsigned)WW && (unsigned)gy < (unsigned)HH) {
                const float4* p = reinterpret_cast<const float4*>(in + ((size_t)gy * WW + gx) * 8);
                a = p[0];
                b = p[1];
            }
            float nn = a.w * a.w + b.x * b.x + b.y * b.y;
            float s = fast_rsq(fmaxf(nn, 1e-20f));
            sA[r][c] = make_float4(a.x, a.y, a.z, a.w * s);
            sN[r][c] = make_float2(b.x * s, b.y * s);
            sZ[r][c] = b.z;
        }
    }
    __syncthreads();

    // ---- per-thread centers: 2 vertically adjacent outputs ----
    float cn0[RPT], cn1[RPT], cn2[RPT], cz[RPT], rdz[RPT];
    #pragma unroll
    for (int o = 0; o < RPT; ++o) {
        int rr = ty * RPT + RAD + o, cc = tx + RAD;
        float4 A = sA[rr][cc];
        float2 N = sN[rr][cc];
        cn0[o] = A.w; cn1[o] = N.x; cn2[o] = N.y; cz[o] = sZ[rr][cc];
        int gy = y0 + ty * RPT + o;
        float dzv = 1.0f;
        if (gy < HH) dzv = in[(((size_t)gy * WW) + (x0 + tx)) * 8 + 7];  // tail-tile guard
        rdz[o] = fminf(1.4426950408889634f * fast_rcp(dzv), 1e10f);  // log2e folded; finite
    }
    const float rr1 = rdz[1] * fast_rcp(rdz[0]);   // chain ratio, finite positive

    float accx[RPT] = {0.f, 0.f};
    float accy[RPT] = {0.f, 0.f};
    float accz[RPT] = {0.f, 0.f};
    float accw[RPT] = {0.f, 0.f};

    // unclamped tm chain state (zero-init: invalid slots chain to 0, gated by val[])
    float tmu0[RAD + 1] = {}, tmu1[RAD + 1] = {};

    // ROW_BODY(CHECK): one tap-row. Rotate the 1-step tm chain, compute 6 fresh rsq
    // for o=0's new dy, clamp into tmv (value-select, compile-time (o,k)), build cxv,
    // then 11 x RPT unrolled bodies with compile-time k = |dx-RAD|.
    // Steady body: 11 VALU + 1 exp2.
    #define ROW_BODY(CHECK)                                                          \
    {                                                                                \
        _Pragma("unroll")                                                            \
        for (int k = 0; k <= RAD; ++k) tmu1[k] = tmu0[k] * rr1;                      \
        if (!CHECK || r <= 2 * RAD) {   /* fresh dy only while it can become valid */\
            int dy0 = r - RAD;                                                      \
            float dy0sq = (float)(dy0 * dy0);                                       \
            _Pragma("unroll")                                                       \
            for (int k = 0; k <= RAD; ++k)                                          \
                tmu0[k] = rdz[0] * fast_rsq(dy0sq + (float)(k * k));                \
        }                                                                            \
        float tmv[RPT][RAD + 1], cxv[RPT][RAD + 1];                                  \
        bool  val[RPT];                                                              \
        _Pragma("unroll")                                                            \
        for (int o = 0; o < RPT; ++o) {                                              \
            int dy = r - RAD - o;                                                    \
            val[o] = (dy >= -RAD) && (dy <= RAD);                                    \
            if (!CHECK || val[o]) {                                                  \
                float dy2f = (float)(dy * dy);                                       \
                float bneg = fmaf(dy2f, -0.18033688011112042f, -276.997447850681f);  \
                _Pragma("unroll")                                                    \
                for (int k = 0; k <= RAD; ++k) {                                     \
                    float tmuk = (o == 0) ? tmu0[k] : tmu1[k];                       \
                    cxv[o][k] = bneg + (float)(k * k) * -0.18033688011112042f;       \
                    tmv[o][k] = fminf(tmuk, 14426.950408889634f);                    \
                }                                                                    \
            }                                                                        \
        }                                                                            \
        _Pragma("unroll")                                                            \
        for (int dx = 0; dx < 2 * RAD + 1; ++dx) {                                   \
            float4 A  = sA[ty * RPT + r][tx + dx];                                   \
            float2 N  = sN[ty * RPT + r][tx + dx];                                   \
            float  tz = sZ[ty * RPT + r][tx + dx];                                   \
            const int k = (dx < RAD) ? (RAD - dx) : (dx - RAD);                      \
            _Pragma("unroll")                                                        \
            for (int o = 0; o < RPT; ++o) {                                          \
                if (!CHECK || val[o]) {                                              \
                    float dot = fmaf(A.w, cn0[o], fmaf(N.x, cn1[o], N.y * cn2[o]));  \
                    float vv  = fmaf(dot, -92.332482616893665f, 369.32993046757466f); \
                    float zd  = tz - cz[o];                                          \
                    float e2a = fmaf(-fabsf(zd), tmv[o][k], cxv[o][k]);              \
                    float e2  = fmaf(dot, vv, e2a);                                  \
                    float w   = fast_exp2(e2);                                       \
                    accx[o] = fmaf(A.x, w, accx[o]);                                 \
                    accy[o] = fmaf(A.y, w, accy[o]);                                 \
                    accz[o] = fmaf(A.z, w, accz[o]);                                 \
                    accw[o] += w;                                                    \
                }                                                                    \
            }                                                                        \
        }                                                                            \
    }

    // ---- boundary head: r=0 (o=1 invalid) ----
    #pragma unroll 1
    for (int r = 0; r < RPT - 1; ++r) ROW_BODY(true)
    // ---- steady rows r in [1,10]: both outputs valid, branch-free ----
    #pragma unroll 1
    for (int r = RPT - 1; r <= 2 * RAD; ++r) ROW_BODY(false)
    // ---- boundary tail: r=11 (o=0 invalid) ----
    #pragma unroll 1
    for (int r = 2 * RAD + 1; r < 2 * RAD + RPT; ++r) ROW_BODY(true)

    #undef ROW_BODY

    // ---- epilogue (y-guard for the partial 68th row-block) ----
    const int xo = x0 + tx;
    #pragma unroll
    for (int o = 0; o < RPT; ++o) {
        int y = y0 + ty * RPT + o;
        if (y < HH) {
            float inv = fast_rcp(accw[o]);
            size_t base = ((size_t)y * WW + xo) * 3;
            out[base + 0] = accx[o] * inv;
            out[base + 1] = accy[o] * inv;
            out[base + 2] = accz[o] * inv;
        }
    }
}

extern "C" void kernel_launch(void* const* d_in, const int* in_sizes, int n_in,
                              void* d_out, int out_size, void* d_ws, size_t ws_size,
                              hipStream_t stream) {
    const float* in = (const float*)d_in[0];
    float* out = (float*)d_out;
    dim3 grid((WW + TX - 1) / TX, (HH + TY - 1) / TY);    // 60 x 68
    dim3 block(TX, BDY);                                   // 256 threads = 4 waves
    hipLaunchKernelGGL(denoise_kernel, grid, block, 0, stream, in, out);
}